// Round 5
// baseline (172.854 us; speedup 1.0000x reference)
//
#include <hip/hip_runtime.h>
#include <stdint.h>
#include <math.h>

// Problem constants (fixed by the reference's setup_inputs)
#define N_BATCH 8
#define A_ELEMS 500000          // anchors per batch
#define TOPK    2000
#define NBINS   2048            // 11-bit histogram of sortable score
#define CAP     4096            // candidate capacity per batch (expected ~3100)
#define BCAP    2048            // per-block candidate capacity
#define BPB     128             // blocks per batch for compact
#define HBLK    32              // hist blocks per batch (private slots, no atomics)
#define HTHR    512             // hist threads per block
#define SEG     16              // key segments for rank phase
#define SEGK    (CAP / SEG)     // 256 keys per segment
#define GRP     4               // candidate groups of 1024 per batch
#define BBOX_CLIP 4.135166556742356f  // log(1000/16)

// Monotone map float -> uint32 (ascending). Larger u <=> larger float.
__device__ __forceinline__ uint32_t f2sortable(float f) {
    uint32_t b = __float_as_uint(f);
    return (b & 0x80000000u) ? ~b : (b | 0x80000000u);
}

// ---------------- pass 1: per-block private histograms ----------------
// No global atomics: each block owns a private 2048-bin slot written with
// plain coalesced stores (also overwrites the harness's 0xAA poison, so no
// zero_kernel needed). LDS uses 4-way sub-bins to break same-address RMW
// serialization within a wave.
__global__ __launch_bounds__(HTHR) void hist_kernel(const float* __restrict__ obj,
                                                    uint32_t* __restrict__ slots) {
    __shared__ uint32_t sh[NBINS * 4];   // 32 KB
    const int n = blockIdx.y, blk = blockIdx.x;
    for (int i = threadIdx.x; i < NBINS * 4; i += HTHR) sh[i] = 0;
    __syncthreads();
    const uint32_t sub = threadIdx.x & 3u;
    const float4* o4 = (const float4*)(obj + (size_t)n * A_ELEMS);
    const int n4 = A_ELEMS / 4;  // 125000, exact
    for (int i = blk * HTHR + (int)threadIdx.x; i < n4; i += HBLK * HTHR) {
        float4 v = o4[i];
        atomicAdd(&sh[((f2sortable(v.x) >> 21) << 2) | sub], 1u);
        atomicAdd(&sh[((f2sortable(v.y) >> 21) << 2) | sub], 1u);
        atomicAdd(&sh[((f2sortable(v.z) >> 21) << 2) | sub], 1u);
        atomicAdd(&sh[((f2sortable(v.w) >> 21) << 2) | sub], 1u);
    }
    __syncthreads();
    uint32_t* slot = slots + ((size_t)n * HBLK + blk) * NBINS;
    for (int i = threadIdx.x; i < NBINS; i += HTHR)
        slot[i] = sh[4*i] + sh[4*i+1] + sh[4*i+2] + sh[4*i+3];   // plain store
}

// ---------------- pass 2: reduce slots + find cutoff bin per batch ----------------
// cut_bin = max B such that sum_{b>=B} hist[b] >= TOPK. Also zeroes cand_count.
__global__ __launch_bounds__(256) void cut_kernel(const uint32_t* __restrict__ slots,
                                                  uint32_t* __restrict__ cut_bin,
                                                  uint32_t* __restrict__ cand_count) {
    __shared__ uint32_t sh[NBINS];
    __shared__ uint32_t chunk[256];
    const int n = blockIdx.x;
    if (threadIdx.x == 0) cand_count[n] = 0;
    const uint32_t* base = slots + (size_t)n * HBLK * NBINS;
    for (int i = threadIdx.x; i < NBINS; i += 256) {
        uint32_t s = 0;
        #pragma unroll 8
        for (int b = 0; b < HBLK; ++b) s += base[(size_t)b * NBINS + i];  // coalesced
        sh[i] = s;
    }
    __syncthreads();
    // chunk t = sum of 8 bins, reversed: t=0 covers the TOP 8 bins
    uint32_t s = 0;
    int hi = NBINS - 8 * (int)threadIdx.x;   // exclusive upper bin
    for (int b = hi - 8; b < hi; ++b) s += sh[b];
    chunk[threadIdx.x] = s;
    __syncthreads();
    if (threadIdx.x == 0) {
        uint32_t cum = 0;
        int t = 0;
        for (t = 0; t < 256; ++t) {
            if (cum + chunk[t] >= TOPK) break;
            cum += chunk[t];
        }
        int b_cut = 0;
        if (t < 256) {
            int hi2 = NBINS - 8 * t;
            for (int b = hi2 - 1; b >= hi2 - 8; --b) {
                cum += sh[b];
                if (cum >= TOPK) { b_cut = b; break; }
            }
        }
        cut_bin[n] = (uint32_t)b_cut;
    }
}

// ---------------- pass 3: compact candidates (bin >= cut_bin) ----------------
// key = (sortable_score << 32) | ~index  -> key desc == score desc, index asc
// Block-local LDS staging; ONE global atomic per block to reserve output slice.
__global__ void compact_kernel(const float* __restrict__ obj,
                               const uint32_t* __restrict__ cut_bin,
                               uint32_t* __restrict__ cand_count,
                               unsigned long long* __restrict__ cand) {
    __shared__ unsigned long long lbuf[BCAP];   // 16 KB
    __shared__ uint32_t lcount;
    __shared__ uint32_t lbase;
    const int n = blockIdx.y;
    if (threadIdx.x == 0) lcount = 0;
    __syncthreads();
    const uint32_t cb = cut_bin[n];
    const float4* o4 = (const float4*)(obj + (size_t)n * A_ELEMS);
    const int n4 = A_ELEMS / 4;
    for (int i = blockIdx.x * blockDim.x + threadIdx.x; i < n4; i += gridDim.x * blockDim.x) {
        float4 v = o4[i];
        uint32_t us[4] = {f2sortable(v.x), f2sortable(v.y), f2sortable(v.z), f2sortable(v.w)};
        #pragma unroll
        for (int c = 0; c < 4; ++c) {
            if ((us[c] >> 21) >= cb) {
                uint32_t pos = atomicAdd(&lcount, 1u);     // LDS atomic — cheap
                if (pos < BCAP) {
                    uint32_t idx = (uint32_t)(i * 4 + c);
                    lbuf[pos] = ((unsigned long long)us[c] << 32) |
                                (unsigned long long)(~idx);
                }
            }
        }
    }
    __syncthreads();
    if (threadIdx.x == 0) {
        uint32_t c = lcount < BCAP ? lcount : BCAP;
        lbase = atomicAdd(&cand_count[n], c);              // one global atomic/block
    }
    __syncthreads();
    unsigned long long* cn = cand + (size_t)n * CAP;
    uint32_t c = lcount < BCAP ? lcount : BCAP;
    uint32_t base = lbase;
    for (uint32_t i = threadIdx.x; i < c; i += blockDim.x) {
        uint32_t p = base + i;
        if (p < CAP) cn[p] = lbuf[i];
    }
}

// ---------------- pass 4a: partial ranks ----------------
// rank(t) = #{j : key_j > key_t}; keys unique -> rank == final sorted position.
// Grid (GRP, SEG, N_BATCH): block computes, for its 1024 candidates (4/thread,
// keys held in registers), the partial count against one 256-key segment held
// in LDS. One broadcast ulonglong2 read feeds 8 compares.
__global__ __launch_bounds__(256) void rank_partial_kernel(
    const uint32_t* __restrict__ cand_count,
    const unsigned long long* __restrict__ cand,
    uint16_t* __restrict__ partial) {
    __shared__ unsigned long long s[SEGK];   // 2 KB
    const int n = blockIdx.z, seg = blockIdx.y, grp = blockIdx.x;
    uint32_t cnt = cand_count[n];
    if (cnt > CAP) cnt = CAP;
    const unsigned long long* cn = cand + (size_t)n * CAP;
    const int ks = seg * SEGK;
    for (int i = threadIdx.x; i < SEGK; i += 256)
        s[i] = ((uint32_t)(ks + i) < cnt) ? cn[ks + i] : 0ull;  // pad 0 < any real key
    __syncthreads();
    const int t0 = grp * 1024 + (int)threadIdx.x;
    // keys for t >= cnt are poison but their ranks are never consumed
    unsigned long long k0 = cn[t0], k1 = cn[t0 + 256], k2 = cn[t0 + 512], k3 = cn[t0 + 768];
    uint32_t r0 = 0, r1 = 0, r2 = 0, r3 = 0;
    const ulonglong2* s2 = (const ulonglong2*)s;
    #pragma unroll 8
    for (int j = 0; j < SEGK / 2; ++j) {
        ulonglong2 p = s2[j];                // wave-uniform broadcast read
        r0 += (p.x > k0); r0 += (p.y > k0);
        r1 += (p.x > k1); r1 += (p.y > k1);
        r2 += (p.x > k2); r2 += (p.y > k2);
        r3 += (p.x > k3); r3 += (p.y > k3);
    }
    uint16_t* pp = partial + ((size_t)n * SEG + seg) * CAP;
    pp[t0]       = (uint16_t)r0;
    pp[t0 + 256] = (uint16_t)r1;
    pp[t0 + 512] = (uint16_t)r2;
    pp[t0 + 768] = (uint16_t)r3;
}

// ---------------- pass 4b: sum partials, gather, decode, write ----------------
__global__ __launch_bounds__(256) void decode_kernel(
    const float* __restrict__ anchors, const float* __restrict__ breg,
    const uint32_t* __restrict__ cand_count,
    const unsigned long long* __restrict__ cand,
    const uint16_t* __restrict__ partial,
    float* __restrict__ out) {
    const int n = blockIdx.y;
    const int t = blockIdx.x * 256 + (int)threadIdx.x;
    uint32_t cnt = cand_count[n];
    if (cnt > CAP) cnt = CAP;
    if ((uint32_t)t >= cnt) return;
    const uint16_t* pp = partial + (size_t)n * SEG * CAP;
    uint32_t rank = 0;
    #pragma unroll
    for (int sg = 0; sg < SEG; ++sg) rank += pp[(size_t)sg * CAP + t];
    if (rank >= TOPK) return;
    const unsigned long long mykey = cand[(size_t)n * CAP + t];
    const uint32_t u    = (uint32_t)(mykey >> 32);
    const uint32_t idx  = ~((uint32_t)mykey);
    const uint32_t bits = (u & 0x80000000u) ? (u ^ 0x80000000u) : ~u;
    const float score = __uint_as_float(bits);
    const float4 a = ((const float4*)anchors)[(size_t)n * A_ELEMS + idx];
    const float4 b = ((const float4*)breg)[(size_t)n * A_ELEMS + idx];
    float w  = a.z - a.x + 1.0f;
    float h  = a.w - a.y + 1.0f;
    float cx = a.x + 0.5f * w;
    float cy = a.y + 0.5f * h;
    float dw = fminf(b.z, BBOX_CLIP);
    float dh = fminf(b.w, BBOX_CLIP);
    float pcx = b.x * w + cx;
    float pcy = b.y * h + cy;
    float pw  = expf(dw) * w;
    float ph  = expf(dh) * h;
    float* row = out + ((size_t)n * TOPK + rank) * 5;
    row[0] = pcx - 0.5f * pw;
    row[1] = pcy - 0.5f * ph;
    row[2] = pcx + 0.5f * pw - 1.0f;
    row[3] = pcy + 0.5f * ph - 1.0f;
    row[4] = score;
}

extern "C" void kernel_launch(void* const* d_in, const int* in_sizes, int n_in,
                              void* d_out, int out_size, void* d_ws, size_t ws_size,
                              hipStream_t stream) {
    const float* anchors    = (const float*)d_in[0];  // [8,500000,4]
    const float* objectness = (const float*)d_in[1];  // [8,500000,1]
    const float* breg       = (const float*)d_in[2];  // [8,500000,4]
    float* out = (float*)d_out;                        // [8,2000,5]

    // Workspace layout:
    //   [0,        2097152)  hist slots  uint32[8][32][2048]  (fully overwritten)
    //   [2097152,  2097184)  cand_count  uint32[8]            (zeroed in cut_kernel)
    //   [2097184,  2097216)  cut_bin     uint32[8]
    //   [2097216,  2359360)  cand        uint64[8][4096]
    //   [2359360,  3407936)  partial     uint16[8][16][4096]  (fully overwritten)
    uint8_t* ws = (uint8_t*)d_ws;
    uint32_t* slots      = (uint32_t*)ws;
    uint32_t* cand_count = (uint32_t*)(ws + 2097152);
    uint32_t* cut_bin    = (uint32_t*)(ws + 2097184);
    unsigned long long* cand = (unsigned long long*)(ws + 2097216);
    uint16_t* partial    = (uint16_t*)(ws + 2359360);

    dim3 gh(HBLK, N_BATCH);
    hist_kernel<<<gh, HTHR, 0, stream>>>(objectness, slots);
    cut_kernel<<<N_BATCH, 256, 0, stream>>>(slots, cut_bin, cand_count);
    dim3 g1(BPB, N_BATCH);
    compact_kernel<<<g1, 256, 0, stream>>>(objectness, cut_bin, cand_count, cand);
    dim3 g2(GRP, SEG, N_BATCH);
    rank_partial_kernel<<<g2, 256, 0, stream>>>(cand_count, cand, partial);
    dim3 g3(CAP / 256, N_BATCH);
    decode_kernel<<<g3, 256, 0, stream>>>(anchors, breg, cand_count, cand, partial, out);
}